// Round 16
// baseline (1499.987 us; speedup 1.0000x reference)
//
#include <hip/hip_runtime.h>
#include <hip/hip_bf16.h>

typedef __hip_bfloat16 bf16;
typedef __attribute__((ext_vector_type(8))) short bf8_t;   // 8 bf16 = 4 VGPR
typedef __attribute__((ext_vector_type(4))) float f4_t;

#define KHK 197376
#define OFF_WIN 0
#define OFF_BIN 49152
#define OFF_WMD 49280
#define OFF_BMD 65664
#define OFF_WOT 65792
#define OFF_BOT 98560
#define OFF_WSC 98816
#define OFF_BSC 197120

__device__ __forceinline__ float ldf(const float* p, size_t i){ return p[i]; }
__device__ __forceinline__ float ldf(const bf16* p, size_t i){ return __bfloat162float(p[i]); }
__device__ __forceinline__ void stf(float* p, size_t i, float v){ p[i] = v; }
__device__ __forceinline__ void stf(bf16* p, size_t i, float v){ p[i] = __float2bfloat16(v); }
__device__ __forceinline__ float b2f(short u){ return __uint_as_float(((unsigned)(unsigned short)u) << 16); }

// async global->LDS, 16B per lane; LDS dest is wave-uniform base + lane*16
typedef const __attribute__((address_space(1))) unsigned int* gas_t;
typedef __attribute__((address_space(3))) unsigned int* las_t;
__device__ __forceinline__ void gld_lds16(const void* g, void* l){
  __builtin_amdgcn_global_load_lds((gas_t)g, (las_t)l, 16, 0, 0);
}

struct Seg { const bf16* p; int klen; int ld; };

// ---------------- fp32 -> bf16 bulk convert (16B stores) ----------------
__global__ __launch_bounds__(256) void k_cvt_bf16(const float* __restrict__ in,
    bf16* __restrict__ out, size_t n){
  size_t stride = (size_t)gridDim.x * 256;
  for (size_t i = blockIdx.x*256ULL + threadIdx.x; i*8 < n; i += stride){
    float4 a = *reinterpret_cast<const float4*>(in + i*8);
    float4 c = *reinterpret_cast<const float4*>(in + i*8 + 4);
    union { bf8_t v; bf16 e[8]; } o;
    o.e[0]=__float2bfloat16(a.x); o.e[1]=__float2bfloat16(a.y);
    o.e[2]=__float2bfloat16(a.z); o.e[3]=__float2bfloat16(a.w);
    o.e[4]=__float2bfloat16(c.x); o.e[5]=__float2bfloat16(c.y);
    o.e[6]=__float2bfloat16(c.z); o.e[7]=__float2bfloat16(c.w);
    *reinterpret_cast<bf8_t*>(out + i*8) = o.v;
  }
}

// ---------------- input 1x1 conv, channel-last out [b][s][128] ----------------
__global__ __launch_bounds__(256) void k_in_conv(const float* __restrict__ x,
    const float* __restrict__ w, const float* __restrict__ b, float* __restrict__ out){
  int idx = blockIdx.x*256 + threadIdx.x;          // 16*4096*128
  int c = idx & 127;
  int s = (idx >> 7) & 4095;
  int bi = idx >> 19;
  const float* xb = x + (size_t)bi*3*4096;
  out[idx] = b[c] + w[c*3]*xb[s] + w[c*3+1]*xb[4096+s] + w[c*3+2]*xb[8192+s];
}

// ------- sobel + concat, float4 (4 ch/thread): OUT[b][s][128] -> P[b][s][384] bf16 -------
__global__ __launch_bounds__(256) void k_sobel4(const float* __restrict__ src,
    bf16* __restrict__ p, int H, int S){
  int idx = blockIdx.x*256 + threadIdx.x;          // 16*S*32 threads
  int c4 = (idx & 31) * 4;
  int s = (idx >> 5) % S;
  int b = idx / (S*32);
  int y = s / H, x = s - y*H;
  const float* sb = src + (size_t)b*S*128 + c4;
  float4 n[3][3];
  #pragma unroll
  for (int dy=0; dy<3; dy++)
    #pragma unroll
    for (int dx=0; dx<3; dx++){
      int yy = y + dy - 1, xx = x + dx - 1;
      if (yy>=0 && yy<H && xx>=0 && xx<H)
        n[dy][dx] = *reinterpret_cast<const float4*>(sb + (size_t)(yy*H+xx)*128);
      else
        n[dy][dx] = (float4){0.f,0.f,0.f,0.f};
    }
  float v0[4], sx[4], sy[4];
  #pragma unroll
  for (int q = 0; q < 4; q++){
    float e00=((const float*)&n[0][0])[q], e01=((const float*)&n[0][1])[q], e02=((const float*)&n[0][2])[q];
    float e10=((const float*)&n[1][0])[q], e11=((const float*)&n[1][1])[q], e12=((const float*)&n[1][2])[q];
    float e20=((const float*)&n[2][0])[q], e21=((const float*)&n[2][1])[q], e22=((const float*)&n[2][2])[q];
    v0[q] = e11;
    sx[q] = (-e00 + e02 - 2.f*e10 + 2.f*e12 - e20 + e22) * 0.125f;
    sy[q] = (-e00 - 2.f*e01 - e02 + e20 + 2.f*e21 + e22) * 0.125f;
  }
  bf16* pb = p + ((size_t)b*S + s)*384;
  union { unsigned long long u; bf16 e[4]; } o0, o1, o2;
  #pragma unroll
  for (int q = 0; q < 4; q++){
    o0.e[q] = __float2bfloat16(v0[q]);
    o1.e[q] = __float2bfloat16(sx[q]);
    o2.e[q] = __float2bfloat16(sy[q]);
  }
  *reinterpret_cast<unsigned long long*>(pb + c4)       = o0.u;
  *reinterpret_cast<unsigned long long*>(pb + 128 + c4) = o1.u;
  *reinterpret_cast<unsigned long long*>(pb + 256 + c4) = o2.u;
}

// ---------------- per-(b,c) sums over s of P: SUMS[b][384][2] (pre-zeroed) ----------------
__global__ __launch_bounds__(256) void k_stats(const bf16* __restrict__ P_,
    float* __restrict__ SUMS, int S){
  __shared__ float sS[384], sQ[384];
  int b = blockIdx.y;
  int chunk = S >> 4;
  int s0 = blockIdx.x * chunk;
  int t = threadIdx.x;
  for (int i = t; i < 384; i += 256){ sS[i] = 0.f; sQ[i] = 0.f; }
  __syncthreads();
  if (t < 240){
    int oct = t % 48, ls = t / 48;
    int c8 = oct*8;
    float as[8] = {}, qs[8] = {};
    for (int s = s0 + ls; s < s0 + chunk; s += 5){
      bf8_t v = *reinterpret_cast<const bf8_t*>(P_ + ((size_t)b*S + s)*384 + c8);
      #pragma unroll
      for (int i=0;i<8;i++){ float f = b2f(v[i]); as[i]+=f; qs[i]+=f*f; }
    }
    #pragma unroll
    for (int i=0;i<8;i++){ atomicAdd(&sS[c8+i], as[i]); atomicAdd(&sQ[c8+i], qs[i]); }
  }
  __syncthreads();
  for (int i = t; i < 384; i += 256){
    atomicAdd(&SUMS[((size_t)b*384+i)*2],   sS[i]);
    atomicAdd(&SUMS[((size_t)b*384+i)*2+1], sQ[i]);
  }
}

// ------- batched hypernet v5: exact r6-v1 loop (96 VGPR, no unroll), bf16 output -------
__global__ __launch_bounds__(256) void k_hyper_all(const float* __restrict__ hw,
    const float* __restrict__ hb, const bf16* __restrict__ latb,   // [12*16][512]
    bf16* __restrict__ hk_all){                                    // [12][16][KHK] bf16
  __shared__ float Sw[128][17];
  int h0 = blockIdx.x * 128;
  int tid = threadIdx.x, wid = tid >> 6, lane = tid & 63;
  int lr = lane & 15, lg = lane >> 4;
  f4_t acc[2][12];
  #pragma unroll
  for (int f=0; f<2; f++)
    #pragma unroll
    for (int j=0; j<12; j++) acc[f][j] = (f4_t){0.f,0.f,0.f,0.f};
  for (int k0 = 0; k0 < 512; k0 += 32){
    bf8_t af[2];
    #pragma unroll
    for (int f = 0; f < 2; f++){
      int h = h0 + wid*32 + f*16 + lr;
      const float* src = hw + (size_t)h*512 + k0 + lg*8;
      float4 x0 = *reinterpret_cast<const float4*>(src);
      float4 x1 = *reinterpret_cast<const float4*>(src + 4);
      union { bf8_t v; bf16 e[8]; } o;
      o.e[0]=__float2bfloat16(x0.x); o.e[1]=__float2bfloat16(x0.y);
      o.e[2]=__float2bfloat16(x0.z); o.e[3]=__float2bfloat16(x0.w);
      o.e[4]=__float2bfloat16(x1.x); o.e[5]=__float2bfloat16(x1.y);
      o.e[6]=__float2bfloat16(x1.z); o.e[7]=__float2bfloat16(x1.w);
      af[f] = o.v;
    }
    #pragma unroll
    for (int j = 0; j < 12; j++){
      bf8_t bv = *reinterpret_cast<const bf8_t*>(latb + (size_t)(j*16 + lr)*512 + k0 + lg*8);
      acc[0][j] = __builtin_amdgcn_mfma_f32_16x16x32_bf16(af[0], bv, acc[0][j], 0, 0, 0);
      acc[1][j] = __builtin_amdgcn_mfma_f32_16x16x32_bf16(af[1], bv, acc[1][j], 0, 0, 0);
    }
  }
  for (int j = 0; j < 12; j++){
    __syncthreads();
    #pragma unroll
    for (int f = 0; f < 2; f++)
      #pragma unroll
      for (int r = 0; r < 4; r++)
        Sw[wid*32 + f*16 + lg*4 + r][lr] = acc[f][j][r];
    __syncthreads();
    int bb = tid >> 4, h8 = (tid & 15) * 8;
    union { bf8_t v; bf16 e[8]; } o;
    #pragma unroll
    for (int i = 0; i < 8; i++)
      o.e[i] = __float2bfloat16(hb[h0 + h8 + i] + Sw[h8 + i][bb]);
    *reinterpret_cast<bf8_t*>(hk_all + ((size_t)j*16 + bb)*KHK + h0 + h8) = o.v;
  }
}

// ---------------- all 12 latc GEMMs in one launch: LATB[c][b][512] bf16 ----------------
__global__ __launch_bounds__(256) void k_latall(const float* __restrict__ inj,
    const float* __restrict__ lat_w, const float* __restrict__ lat_b,
    bf16* __restrict__ LATB){
  int gwave = (int)((blockIdx.x*256 + threadIdx.x) >> 6);   // 0..6143
  int lane = threadIdx.x & 63;
  int c = gwave >> 9, o = gwave & 511;
  const float* wr = lat_w + (size_t)c*262144 + (size_t)o*512;
  float acc[16] = {};
  for (int k = lane; k < 512; k += 64){
    float wv = wr[k];
    #pragma unroll
    for (int b = 0; b < 16; b++) acc[b] += wv * inj[b*512 + k];
  }
  #pragma unroll
  for (int b = 0; b < 16; b++)
    for (int off = 32; off > 0; off >>= 1) acc[b] += __shfl_down(acc[b], off);
  if (lane == 0){
    float bv = lat_b[c*512 + o];
    #pragma unroll
    for (int b = 0; b < 16; b++)
      LATB[(size_t)c*8192 + b*512 + o] = __float2bfloat16(acc[b] + bv);
  }
}

// ------ weight transform (HK bf16): fold instnorm, stacked mats, a/g interleave ----
__global__ __launch_bounds__(256) void k_xform(
    const float* __restrict__ fc_w1, const float* __restrict__ fc_b1,
    const float* __restrict__ fc_w2, const float* __restrict__ fc_b2,
    const float* __restrict__ fc_wsc, const float* __restrict__ fc_bsc,
    const bf16* __restrict__ HK_, const float* __restrict__ SUMS, float Sf,
    bf16* __restrict__ Wstack, float* __restrict__ bstack,
    bf16* __restrict__ Wbig, float* __restrict__ bbig,
    bf16* __restrict__ Wmd, float* __restrict__ bmd){
  int gw = (blockIdx.x*256 + threadIdx.x) >> 6;
  int lane = threadIdx.x & 63;
  float invSf = 1.f / Sf;
  if (gw < 4096){                     // Wstack rows: [fc_w1 ; w_in] per batch
    int b = gw >> 8, o = gw & 255;
    const float* su = SUMS + (size_t)b*768;
    const bf16* hkb = HK_ + (size_t)b*KHK;
    float b0 = (o < 128) ? fc_b1[o] : ldf(hkb, OFF_BIN + (o-128));
    float accv = 0.f;
    bf16* dst = Wstack + ((size_t)b*256 + o)*384;
    for (int k = lane; k < 384; k += 64){
      float m = su[k*2] * invSf;
      float iv = rsqrtf(fmaxf(su[k*2+1]*invSf - m*m, 0.f) + 1e-5f);
      float wv = (o < 128) ? fc_w1[(size_t)o*384 + k]
                           : ldf(hkb, OFF_WIN + (size_t)(o-128)*384 + k);
      float w = wv * iv;
      accv += w * m;
      dst[k] = __float2bfloat16(w);
    }
    for (int off=32; off>0; off>>=1) accv += __shfl_down(accv, off);
    if (lane==0) bstack[b*256+o] = b0 - accv;
  } else if (gw < 8192){              // Wbig rows: [fc_wsc+w_sc | fc_w2 | w_ot], a/g interleave
    int r = gw - 4096; int b = r >> 8, o = r & 255;
    const float* su = SUMS + (size_t)b*768;
    const bf16* hkb = HK_ + (size_t)b*KHK;
    int cc = o & 127;
    int nr = ((cc >> 4) << 5) + ((o >> 7) << 4) + (cc & 15);   // 16-row a/g interleave
    bf16* dst = Wbig + ((size_t)b*256 + nr)*640;
    float accv = 0.f;
    for (int k = lane; k < 384; k += 64){
      float m = su[k*2] * invSf;
      float iv = rsqrtf(fmaxf(su[k*2+1]*invSf - m*m, 0.f) + 1e-5f);
      float w = (fc_wsc[(size_t)o*384 + k] + ldf(hkb, OFF_WSC + (size_t)o*384 + k)) * iv;
      accv += w * m;
      dst[k] = __float2bfloat16(w);
    }
    for (int k = lane; k < 128; k += 64){
      dst[384+k] = __float2bfloat16(fc_w2[(size_t)o*128 + k]);
      dst[512+k] = hkb[OFF_WOT + (size_t)o*128 + k];
    }
    for (int off=32; off>0; off>>=1) accv += __shfl_down(accv, off);
    if (lane==0) bbig[b*256+nr] = fc_bsc[o] + ldf(hkb, OFF_BSC+o) + fc_b2[o]
                                  + ldf(hkb, OFF_BOT+o) - accv;
  } else {                            // Wmd rows
    int r = gw - 8192; int b = r >> 7, o = r & 127;
    const bf16* hkb = HK_ + (size_t)b*KHK;
    bf16* dst = Wmd + ((size_t)b*128 + o)*128;
    for (int k = lane; k < 128; k += 64)
      dst[k] = hkb[OFF_WMD + (size_t)o*128 + k];
    if (lane==0) bmd[b*128+o] = ldf(hkb, OFF_BMD + o);
  }
}

// ------ gemm1 512-thread: full 256-n tile, P read once. HG = relu(bstack + P*Wstack) ------
__global__ __launch_bounds__(512) void k_gemm1(const bf16* __restrict__ P_,
    const bf16* __restrict__ W, const float* __restrict__ bias,
    bf16* __restrict__ HGo, int S){
  __shared__ short As[128][32];
  __shared__ short Bs[256][32];
  int b = blockIdx.z, s0 = blockIdx.x * 128;
  int tid = threadIdx.x, wid = tid >> 6, lane = tid & 63;
  int wrow = (wid >> 2) * 64, wcol = (wid & 3) * 64;
  int lr = lane & 15, lg = lane >> 4;
  int r0 = tid >> 2, c8 = (tid & 3) * 8;
  const bf16* Wb = W + (size_t)b * 98304;
  f4_t acc[4][4] = {{}};
  const bf16* gA  = P_ + ((size_t)b*S + s0 + r0) * 384 + c8;
  const bf16* gB0 = Wb + (size_t)r0 * 384 + c8;
  const bf16* gB1 = Wb + (size_t)(128 + r0) * 384 + c8;
  for (int k0 = 0; k0 < 384; k0 += 32){
    gld_lds16(gA + k0,  &As[wid*16][0]);
    gld_lds16(gB0 + k0, &Bs[wid*16][0]);
    gld_lds16(gB1 + k0, &Bs[128 + wid*16][0]);
    __syncthreads();
    bf8_t af[4], bfv[4];
    #pragma unroll
    for (int i = 0; i < 4; i++) af[i]  = *(const bf8_t*)(&As[wrow + i*16 + lr][lg*8]);
    #pragma unroll
    for (int j = 0; j < 4; j++) bfv[j] = *(const bf8_t*)(&Bs[wcol + j*16 + lr][lg*8]);
    #pragma unroll
    for (int i = 0; i < 4; i++)
      #pragma unroll
      for (int j = 0; j < 4; j++)
        acc[i][j] = __builtin_amdgcn_mfma_f32_16x16x32_bf16(af[i], bfv[j], acc[i][j], 0, 0, 0);
    __syncthreads();
  }
  #pragma unroll
  for (int j = 0; j < 4; j++){
    int n = wcol + j*16 + lr;
    float bv = bias[(size_t)b * 256 + n];
    #pragma unroll
    for (int i = 0; i < 4; i++){
      int sr = s0 + wrow + i*16 + lg*4;
      size_t base = ((size_t)b * S + sr) * 256 + n;
      #pragma unroll
      for (int r = 0; r < 4; r++)
        stf(HGo, base + (size_t)r * 256, fmaxf(acc[i][j][r] + bv, 0.f));
    }
  }
}

// ------ gemm23 512-thread: phase A (G2 tile once) + gated 3-seg phase B, P read once ------
__global__ __launch_bounds__(512) void k_gemm23(
    const bf16* __restrict__ P_, const bf16* __restrict__ HG_,
    const bf16* __restrict__ Wmd, const float* __restrict__ bmd,
    const bf16* __restrict__ Wbig, const float* __restrict__ bbig,
    float* __restrict__ OUTf, int S, const float* __restrict__ leakp){
  __shared__ short As[128][32];
  __shared__ short Bs[256][32];
  __shared__ short G2t[128][136];
  int b = blockIdx.z, s0 = blockIdx.x * 128;
  int tid = threadIdx.x, wid = tid >> 6, lane = tid & 63;
  int lr = lane & 15, lg = lane >> 4;
  int r0 = tid >> 2, c8 = (tid & 3) * 8;
  bf16* G2b = (bf16*)&G2t[0][0];
  // ---- phase A: G2 = relu(bmd + Hm*Wmd); per-wave 32s x 64n (4x2 wave grid)
  {
    int wrowA = (wid >> 1) * 32, wcolA = (wid & 1) * 64;
    f4_t accA[2][4] = {{}};
    const bf16* gA = HG_ + ((size_t)b*S + s0 + r0) * 256 + 128 + c8;
    const bf16* gB = Wmd + (size_t)b*16384 + (size_t)r0 * 128 + c8;
    for (int k0 = 0; k0 < 128; k0 += 32){
      gld_lds16(gA + k0, &As[wid*16][0]);
      gld_lds16(gB + k0, &Bs[wid*16][0]);   // 128 rows, one full-block pass
      __syncthreads();
      bf8_t af[2], bfv[4];
      #pragma unroll
      for (int i = 0; i < 2; i++) af[i]  = *(const bf8_t*)(&As[wrowA + i*16 + lr][lg*8]);
      #pragma unroll
      for (int j = 0; j < 4; j++) bfv[j] = *(const bf8_t*)(&Bs[wcolA + j*16 + lr][lg*8]);
      #pragma unroll
      for (int i = 0; i < 2; i++)
        #pragma unroll
        for (int j = 0; j < 4; j++)
          accA[i][j] = __builtin_amdgcn_mfma_f32_16x16x32_bf16(af[i], bfv[j], accA[i][j], 0, 0, 0);
      __syncthreads();
    }
    const float* bmdb = bmd + b*128;
    #pragma unroll
    for (int j = 0; j < 4; j++){
      int col = wcolA + j*16 + lr;
      float bv = bmdb[col];
      #pragma unroll
      for (int i = 0; i < 2; i++){
        int row = wrowA + i*16 + lg*4;
        #pragma unroll
        for (int r = 0; r < 4; r++)
          stf(G2b, (size_t)(row + r)*136 + col, fmaxf(accA[i][j][r] + bv, 0.f));
      }
    }
    __syncthreads();
  }
  // ---- phase B: segs {P(384), H1=HG[:,0:128](128), G2t(128 LDS)}; 2x4 wave grid
  int wrow = (wid >> 2) * 64, wcol = (wid & 3) * 64;
  f4_t acc[4][4] = {{}};
  const bf16* Wb = Wbig + (size_t)b * 163840;
  {   // seg 1: P
    const bf16* gA  = P_ + ((size_t)b*S + s0 + r0) * 384 + c8;
    const bf16* gB0 = Wb + (size_t)r0 * 640 + c8;
    const bf16* gB1 = Wb + (size_t)(128 + r0) * 640 + c8;
    for (int k0 = 0; k0 < 384; k0 += 32){
      gld_lds16(gA + k0,  &As[wid*16][0]);
      gld_lds16(gB0 + k0, &Bs[wid*16][0]);
      gld_lds16(gB1 + k0, &Bs[128 + wid*16][0]);
      __syncthreads();
      bf8_t af[4], bfv[4];
      #pragma unroll
      for (int i = 0; i < 4; i++) af[i]  = *(const bf8_t*)(&As[wrow + i*16 + lr][lg*8]);
      #pragma unroll
      for (int j = 0; j < 4; j++) bfv[j] = *(const bf8_t*)(&Bs[wcol + j*16 + lr][lg*8]);
      #pragma unroll
      for (int i = 0; i < 4; i++)
        #pragma unroll
        for (int j = 0; j < 4; j++)
          acc[i][j] = __builtin_amdgcn_mfma_f32_16x16x32_bf16(af[i], bfv[j], acc[i][j], 0, 0, 0);
      __syncthreads();
    }
  }
  {   // seg 2: H1 = HG cols 0..128
    const bf16* gA  = HG_ + ((size_t)b*S + s0 + r0) * 256 + c8;
    const bf16* gB0 = Wb + (size_t)r0 * 640 + 384 + c8;
    const bf16* gB1 = Wb + (size_t)(128 + r0) * 640 + 384 + c8;
    for (int k0 = 0; k0 < 128; k0 += 32){
      gld_lds16(gA + k0,  &As[wid*16][0]);
      gld_lds16(gB0 + k0, &Bs[wid*16][0]);
      gld_lds16(gB1 + k0, &Bs[128 + wid*16][0]);
      __syncthreads();
      bf8_t af[4], bfv[4];
      #pragma unroll
      for (int i = 0; i < 4; i++) af[i]  = *(const bf8_t*)(&As[wrow + i*16 + lr][lg*8]);
      #pragma unroll
      for (int j = 0; j < 4; j++) bfv[j] = *(const bf8_t*)(&Bs[wcol + j*16 + lr][lg*8]);
      #pragma unroll
      for (int i = 0; i < 4; i++)
        #pragma unroll
        for (int j = 0; j < 4; j++)
          acc[i][j] = __builtin_amdgcn_mfma_f32_16x16x32_bf16(af[i], bfv[j], acc[i][j], 0, 0, 0);
      __syncthreads();
    }
  }
  {   // seg 3: G2 tile from LDS (A), Wbig cols 512..640 (B staged)
    const bf16* gB0 = Wb + (size_t)r0 * 640 + 512 + c8;
    const bf16* gB1 = Wb + (size_t)(128 + r0) * 640 + 512 + c8;
    for (int k0 = 0; k0 < 128; k0 += 32){
      gld_lds16(gB0 + k0, &Bs[wid*16][0]);
      gld_lds16(gB1 + k0, &Bs[128 + wid*16][0]);
      __syncthreads();
      bf8_t af[4], bfv[4];
      #pragma unroll
      for (int i = 0; i < 4; i++) af[i]  = *(const bf8_t*)(&G2t[wrow + i*16 + lr][k0 + lg*8]);
      #pragma unroll
      for (int j = 0; j < 4; j++) bfv[j] = *(const bf8_t*)(&Bs[wcol + j*16 + lr][lg*8]);
      #pragma unroll
      for (int i = 0; i < 4; i++)
        #pragma unroll
        for (int j = 0; j < 4; j++)
          acc[i][j] = __builtin_amdgcn_mfma_f32_16x16x32_bf16(af[i], bfv[j], acc[i][j], 0, 0, 0);
      __syncthreads();
    }
  }
  // gated epilogue: interleaved a/g cols -> OUT += leak*a*sigmoid(g)
  float leak = fminf(fmaxf(leakp[0], 0.001f), 1000.f);
  #pragma unroll
  for (int jp = 0; jp < 2; jp++){
    int na = wcol + jp*32 + lr;
    float bva = bbig[(size_t)b * 256 + na];
    float bvg = bbig[(size_t)b * 256 + na + 16];
    int chan = (wcol >> 1) + jp*16 + lr;
    #pragma unroll
    for (int i = 0; i < 4; i++){
      int sr = s0 + wrow + i*16 + lg*4;
      #pragma unroll
      for (int r = 0; r < 4; r++){
        float av = acc[i][jp*2][r]   + bva;
        float gv = acc[i][jp*2+1][r] + bvg;
        size_t oidx = ((size_t)b * S + sr + r) * 128 + chan;
        OUTf[oidx] += leak * av * (1.f / (1.f + expf(-gv)));
      }
    }
  }
}

// ------ head MFMA GEMM (256-thread, m97 staging) ------
template<int RELU, class TOUT>
__global__ __launch_bounds__(256) void k_mfgemm(
    Seg s1, const bf16* __restrict__ W, long long wbstride, int Ktot,
    const float* __restrict__ bias, int bbstride,
    TOUT* __restrict__ OUTp, int ldc, int Mout, int S){
  __shared__ short As[128][32];
  __shared__ short Bs[128][32];
  int b  = blockIdx.z;
  int s0 = blockIdx.x * 128;
  int n0 = blockIdx.y * 128;
  int tid = threadIdx.x;
  int wid = tid >> 6, lane = tid & 63;
  int wrow = (wid >> 1) * 64;
  int wcol = (wid & 1) * 64;
  int lr = lane & 15, lg = lane >> 4;
  int r0 = wid*32 + (lane >> 2);
  int c8 = (lane & 3) * 8;
  const bf16* Wb = W + (size_t)b * wbstride;
  f4_t acc[4][4] = {{}};
  const bf16* INb = s1.p + (size_t)b * S * s1.ld;
  const bf16* gA0 = INb + (size_t)(s0 + r0) * s1.ld + c8;
  const bf16* gA1 = INb + (size_t)(s0 + r0 + 16) * s1.ld + c8;
  const bf16* gB0 = Wb + (size_t)(n0 + r0) * Ktot + c8;
  const bf16* gB1 = Wb + (size_t)(n0 + r0 + 16) * Ktot + c8;
  for (int k0 = 0; k0 < s1.klen; k0 += 32){
    gld_lds16(gA0 + k0, &As[wid*32][0]);
    gld_lds16(gA1 + k0, &As[wid*32 + 16][0]);
    gld_lds16(gB0 + k0, &Bs[wid*32][0]);
    gld_lds16(gB1 + k0, &Bs[wid*32 + 16][0]);
    __syncthreads();
    bf8_t af[4], bfv[4];
    #pragma unroll
    for (int i = 0; i < 4; i++) af[i]  = *(const bf8_t*)(&As[wrow + i*16 + lr][lg*8]);
    #pragma unroll
    for (int j = 0; j < 4; j++) bfv[j] = *(const bf8_t*)(&Bs[wcol + j*16 + lr][lg*8]);
    #pragma unroll
    for (int i = 0; i < 4; i++)
      #pragma unroll
      for (int j = 0; j < 4; j++)
        acc[i][j] = __builtin_amdgcn_mfma_f32_16x16x32_bf16(af[i], bfv[j], acc[i][j], 0, 0, 0);
    __syncthreads();
  }
  #pragma unroll
  for (int j = 0; j < 4; j++){
    int n = n0 + wcol + j*16 + lr;
    if (n >= Mout) continue;
    float bv = bias[(size_t)b * bbstride + n];
    #pragma unroll
    for (int i = 0; i < 4; i++){
      int sr = s0 + wrow + i*16 + lg*4;
      size_t base = ((size_t)b * S + sr) * ldc + n;
      #pragma unroll
      for (int r = 0; r < 4; r++){
        float v = acc[i][j][r] + bv;
        if (RELU) v = fmaxf(v, 0.f);
        stf(OUTp, base + (size_t)r * ldc, v);
      }
    }
  }
}

// ---------------- fused gaussian blur + 2x2 mean pool, channel-last ----------------
__global__ __launch_bounds__(256) void k_blurpool(const float* __restrict__ src,
    float* __restrict__ dst, int H2, int S2){
  const float g[3] = {0.27406862f, 0.45186276f, 0.27406862f};
  int idx = blockIdx.x*256 + threadIdx.x;   // 16*S2*128
  int c = idx & 127;
  int s2 = (idx >> 7) % S2;
  int b = idx / (S2*128);
  int y2 = s2 / H2, x2 = s2 - y2*H2;
  int H = H2*2;
  const float* sb = src + (size_t)b*(H*H)*128 + c;
  float acc = 0.f;
  #pragma unroll
  for (int dy2 = 0; dy2 < 2; dy2++)
    #pragma unroll
    for (int dx2 = 0; dx2 < 2; dx2++){
      int y = 2*y2 + dy2, x = 2*x2 + dx2;
      float bl = 0.f;
      #pragma unroll
      for (int i = 0; i < 3; i++)
        #pragma unroll
        for (int j = 0; j < 3; j++){
          int yy = y + i - 1, xx = x + j - 1;
          float v = (yy>=0 && yy<H && xx>=0 && xx<H) ? sb[(size_t)(yy*H+xx)*128] : 0.f;
          bl += v * g[i] * g[j];
        }
      acc += bl;
    }
  dst[idx] = acc * 0.25f;
}

// ---------------- add seed + fp32->bf16 in one pass ----------------
__global__ __launch_bounds__(256) void k_seedcvt(const float* __restrict__ in,
    const float* __restrict__ seed, bf16* __restrict__ out){
  int idx = blockIdx.x*256 + threadIdx.x;   // 16*256*128
  int c = idx & 127;
  int s = (idx >> 7) & 255;
  out[idx] = __float2bfloat16(in[idx] + seed[c*256 + s]);
}

// ---------------- build cs (16,4480) from Ohead [16][256][385] ----------------
__global__ __launch_bounds__(256) void k_build_cs(const float* __restrict__ O,
    float* __restrict__ cs){
  int b = blockIdx.x;
  const float* Ob = O + (size_t)b*256*385;
  for (int id = threadIdx.x; id < 4480; id += 256){
    float v;
    if (id < 128){
      float s = 0; for (int t = 0; t < 256; t++) s += Ob[(size_t)t*385 + id];
      v = s * (1.f/256.f);
    } else if (id < 2176){
      int r = id - 128; int c = r >> 4, h = r & 15;
      float s = 0; for (int w = 0; w < 16; w++) s += Ob[(size_t)(h*16+w)*385 + 128 + c];
      v = s * (1.f/16.f);
    } else if (id < 4224){
      int r = id - 2176; int c = r >> 4, w = r & 15;
      float s = 0; for (int h = 0; h < 16; h++) s += Ob[(size_t)(h*16+w)*385 + 256 + c];
      v = s * (1.f/16.f);
    } else {
      v = Ob[(size_t)(id - 4224)*385 + 384];
    }
    cs[b*4480 + id] = v;
  }
}

// ---------------- small 16-row GEMM: one wave per output row of W ----------------
template<int RELU, int ACCUM, class TOUT>
__global__ __launch_bounds__(256) void k_rowgemm(const float* __restrict__ IN, // [16][K]
    const float* __restrict__ W,    // [M][K]
    const float* __restrict__ bias, // [M]
    TOUT* __restrict__ OUT, int M, int K){
  int wave = (int)((blockIdx.x*256 + threadIdx.x) >> 6);
  int lane = threadIdx.x & 63;
  if (wave >= M) return;
  const float* wr = W + (size_t)wave*K;
  float acc[16] = {};
  for (int k = lane; k < K; k += 64){
    float wv = wr[k];
    #pragma unroll
    for (int b = 0; b < 16; b++) acc[b] += wv * IN[b*K + k];
  }
  #pragma unroll
  for (int b = 0; b < 16; b++)
    for (int off = 32; off > 0; off >>= 1) acc[b] += __shfl_down(acc[b], off);
  if (lane == 0){
    float bv = bias[wave];
    #pragma unroll
    for (int b = 0; b < 16; b++){
      float v = acc[b] + bv;
      if (RELU) v = fmaxf(v, 0.f);
      size_t oi = (size_t)b*M + wave;
      if (ACCUM) v += ldf(OUT, oi);
      stf(OUT, oi, v);
    }
  }
}

// ------- dual 16-row GEMM: waves [0,M1) -> set1 (RELU1), waves [M1,M1+M2) -> set2 -------
template<int RELU1>
__global__ __launch_bounds__(256) void k_rowgemm2(const float* __restrict__ IN,
    const float* __restrict__ W1, const float* __restrict__ b1, float* __restrict__ O1, int M1,
    const float* __restrict__ W2, const float* __restrict__ b2, float* __restrict__ O2, int M2,
    int K){
  int wave = (int)((blockIdx.x*256 + threadIdx.x) >> 6);
  int lane = threadIdx.x & 63;
  if (wave >= M1 + M2) return;
  int second = (wave >= M1);
  int o = second ? (wave - M1) : wave;
  const float* wr = (second ? W2 : W1) + (size_t)o*K;
  float acc[16] = {};
  for (int k = lane; k < K; k += 64){
    float wv = wr[k];
    #pragma unroll
    for (int b = 0; b < 16; b++) acc[b] += wv * IN[b*K + k];
  }
  #pragma unroll
  for (int b = 0; b < 16; b++)
    for (int off = 32; off > 0; off >>= 1) acc[b] += __shfl_down(acc[b], off);
  if (lane == 0){
    float bv = second ? b2[o] : b1[o];
    float* OUT = second ? O2 : O1;
    int M = second ? M2 : M1;
    #pragma unroll
    for (int b = 0; b < 16; b++){
      float v = acc[b] + bv;
      if (RELU1 && !second) v = fmaxf(v, 0.f);
      OUT[(size_t)b*M + o] = v;
    }
  }
}

extern "C" void kernel_launch(void* const* d_in, const int* in_sizes, int n_in,
                              void* d_out, int out_size, void* d_ws, size_t ws_size,
                              hipStream_t stream){
  (void)in_sizes; (void)n_in; (void)out_size; (void)ws_size;
  const float* x      = (const float*)d_in[0];
  const float* inj    = (const float*)d_in[1];
  const float* leakp  = (const float*)d_in[2];
  const float* in_w   = (const float*)d_in[3];
  const float* in_b   = (const float*)d_in[4];
  const float* fc_w1  = (const float*)d_in[5];
  const float* fc_b1  = (const float*)d_in[6];
  const float* fc_w2  = (const float*)d_in[7];
  const float* fc_b2  = (const float*)d_in[8];
  const float* fc_wsc = (const float*)d_in[9];
  const float* fc_bsc = (const float*)d_in[10];
  const float* hyp_w  = (const float*)d_in[11];
  const float* hyp_b  = (const float*)d_in[12];
  const float* lat_w  = (const float*)d_in[13];
  const float* lat_b  = (const float*)d_in[14];
  const float* seed   = (const float*)d_in[15];
  const float* out_w  = (const float*)d_in[16];
  const float* out_b  = (const float*)d_in[17];
  const float* l1_w1  = (const float*)d_in[18];
  const float* l1_b1  = (const float*)d_in[19];
  const float* l1_w2  = (const float*)d_in[20];
  const float* l1_b2  = (const float*)d_in[21];
  const float* l1_wsc = (const float*)d_in[22];
  const float* l1_bsc = (const float*)d_in[23];
  const float* l2_w1  = (const float*)d_in[24];
  const float* l2_b1  = (const float*)d_in[25];
  const float* l2_w2  = (const float*)d_in[26];
  const float* l2_b2  = (const float*)d_in[27];
  const float* l2_wsc = (const float*)d_in[28];
  const float* l2_bsc = (const float*)d_in[29];
  const float* fin_w  = (const float*)d_in[30];
  const float* fin_b  = (const float*)d_in[31];

  char* ws = (char*)d_ws;
  float* OUT    = (float*)(ws);                      // 32MB  [16][4096][128] fp32
  bf16*  P      = (bf16*)(ws + 33554432UL);          // 48MB  [16][4096][384]
  bf16*  HG     = (bf16*)(ws + 83886080UL);          // 32MB  [16][4096][256]
  bf16*  HKALL  = (bf16*)(ws + 134217728UL);         // 75.8MB [12][16][197376] bf16
  bf16*  WSTK   = (bf16*)(ws + 285802496UL);         // 3.1MB [16][256][384]
  bf16*  WBIG   = (bf16*)(ws + 288948224UL);         // 5.2MB [16][256][640]
  bf16*  WMD    = (bf16*)(ws + 294191104UL);         // 512KB [16][128][128]
  float* BSTK   = (float*)(ws + 294715392UL);        // [16][256]
  float* BBIG   = (float*)(ws + 294731776UL);        // [16][256]
  float* BMD    = (float*)(ws + 294748160UL);        // [16][128]
  bf16*  LATB   = (bf16*)(ws + 294805504UL);         // [12][16][512]
  bf16*  OUTB   = (bf16*)(ws + 295002112UL);         // [16][256][128]
  float* OHEAD  = (float*)(ws + 296050688UL);        // [16][256][385]
  bf16*  OWB    = (bf16*)(ws + 302358528UL);         // [385][128]
  float* CS     = (float*)(ws + 302457088UL);        // [16][4480]
  float* T1     = (float*)(ws + 302743808UL);        // [16][1024]
  float* HCS    = (float*)(ws + 302809344UL);        // [16][512]
  float* HCS2   = (float*)(ws + 302842112UL);        // [16][512]
  float* SUMS12 = (float*)(ws + 302874880UL);        // 576KB [12][16][384][2]
  float* OUT2   = (float*)(ws + 310378496UL);        // 32MB alt state buffer

  k_cvt_bf16<<<32, 256, 0, stream>>>(out_w, OWB, 49280ULL);
  k_in_conv<<<32768, 256, 0, stream>>>(x, in_w, in_b, OUT);

  k_latall<<<1536, 256, 0, stream>>>(inj, lat_w, lat_b, LATB);
  k_hyper_all<<<1542, 256, 0, stream>>>(hyp_w, hyp_b, LATB, HKALL);
  (void)hipMemsetAsync(SUMS12, 0, 12*16*384*2*sizeof(float), stream);   // all cells, once

  float* cur = OUT;
  float* alt = OUT2;
  int H = 64;
  for (int c = 0; c < 12; c++){
    int S = H*H;
    float* SUMS = SUMS12 + (size_t)c*16*768;
    k_sobel4<<<(16*S*32)/256, 256, 0, stream>>>(cur, P, H, S);
    k_stats<<<dim3(16,16), 256, 0, stream>>>(P, SUMS, S);
    k_xform<<<2560, 256, 0, stream>>>(fc_w1, fc_b1, fc_w2, fc_b2, fc_wsc, fc_bsc,
                                      HKALL + (size_t)c*16*KHK, SUMS, (float)S,
                                      WSTK, BSTK, WBIG, BBIG, WMD, BMD);
    k_gemm1<<<dim3(S/128, 1, 16), 512, 0, stream>>>(P, WSTK, BSTK, HG, S);
    k_gemm23<<<dim3(S/128, 1, 16), 512, 0, stream>>>(
        P, HG, WMD, BMD, WBIG, BBIG, cur, S, leakp);
    if (c == 3 || c == 7){
      int H2 = H/2, S2 = S/4;
      k_blurpool<<<(16*S2*128)/256, 256, 0, stream>>>(cur, alt, H2, S2);
      float* t = cur; cur = alt; alt = t;
      H = H2;
    }
  }

  k_seedcvt<<<2048, 256, 0, stream>>>(cur, seed, OUTB);
  Seg segO = {OUTB, 128, 128};
  k_mfgemm<0,float><<<dim3(2, 4, 16), 256, 0, stream>>>(
      segO, OWB, 0LL, 128, out_b, 0, OHEAD, 385, 385, 256);
  k_build_cs<<<16, 256, 0, stream>>>(OHEAD, CS);

  // head MLP: 5 launches (dual-matrix fusion where inputs match)
  k_rowgemm2<1><<<384, 256, 0, stream>>>(CS, l1_w1, l1_b1, T1, 1024,
                                         l1_wsc, l1_bsc, HCS, 512, 4480);
  k_rowgemm<0,1,float><<<128, 256, 0, stream>>>(T1, l1_w2, l1_b2, HCS, 512, 1024);
  k_rowgemm2<1><<<256, 256, 0, stream>>>(HCS, l2_w1, l2_b1, T1, 512,
                                         l2_wsc, l2_bsc, HCS2, 512, 512);
  k_rowgemm<0,1,float><<<128, 256, 0, stream>>>(T1, l2_w2, l2_b2, HCS2, 512, 512);
  k_rowgemm<0,0,float><<<128, 256, 0, stream>>>(HCS2, fin_w, fin_b, (float*)d_out, 512, 512);
}

// Round 17
// 1436.017 us; speedup vs baseline: 1.0445x; 1.0445x over previous
//
#include <hip/hip_runtime.h>
#include <hip/hip_bf16.h>

typedef __hip_bfloat16 bf16;
typedef __attribute__((ext_vector_type(8))) short bf8_t;   // 8 bf16 = 4 VGPR
typedef __attribute__((ext_vector_type(4))) float f4_t;

#define KHK 197376
#define OFF_WIN 0
#define OFF_BIN 49152
#define OFF_WMD 49280
#define OFF_BMD 65664
#define OFF_WOT 65792
#define OFF_BOT 98560
#define OFF_WSC 98816
#define OFF_BSC 197120

__device__ __forceinline__ float ldf(const float* p, size_t i){ return p[i]; }
__device__ __forceinline__ float ldf(const bf16* p, size_t i){ return __bfloat162float(p[i]); }
__device__ __forceinline__ void stf(float* p, size_t i, float v){ p[i] = v; }
__device__ __forceinline__ void stf(bf16* p, size_t i, float v){ p[i] = __float2bfloat16(v); }
__device__ __forceinline__ float b2f(short u){ return __uint_as_float(((unsigned)(unsigned short)u) << 16); }

// async global->LDS, 16B per lane; LDS dest is wave-uniform base + lane*16
typedef const __attribute__((address_space(1))) unsigned int* gas_t;
typedef __attribute__((address_space(3))) unsigned int* las_t;
__device__ __forceinline__ void gld_lds16(const void* g, void* l){
  __builtin_amdgcn_global_load_lds((gas_t)g, (las_t)l, 16, 0, 0);
}

struct Seg { const bf16* p; int klen; int ld; };

// ---------------- fp32 -> bf16 bulk convert (16B stores) ----------------
__global__ __launch_bounds__(256) void k_cvt_bf16(const float* __restrict__ in,
    bf16* __restrict__ out, size_t n){
  size_t stride = (size_t)gridDim.x * 256;
  for (size_t i = blockIdx.x*256ULL + threadIdx.x; i*8 < n; i += stride){
    float4 a = *reinterpret_cast<const float4*>(in + i*8);
    float4 c = *reinterpret_cast<const float4*>(in + i*8 + 4);
    union { bf8_t v; bf16 e[8]; } o;
    o.e[0]=__float2bfloat16(a.x); o.e[1]=__float2bfloat16(a.y);
    o.e[2]=__float2bfloat16(a.z); o.e[3]=__float2bfloat16(a.w);
    o.e[4]=__float2bfloat16(c.x); o.e[5]=__float2bfloat16(c.y);
    o.e[6]=__float2bfloat16(c.z); o.e[7]=__float2bfloat16(c.w);
    *reinterpret_cast<bf8_t*>(out + i*8) = o.v;
  }
}

// ---------------- input 1x1 conv, channel-last out [b][s][128] ----------------
__global__ __launch_bounds__(256) void k_in_conv(const float* __restrict__ x,
    const float* __restrict__ w, const float* __restrict__ b, float* __restrict__ out){
  int idx = blockIdx.x*256 + threadIdx.x;          // 16*4096*128
  int c = idx & 127;
  int s = (idx >> 7) & 4095;
  int bi = idx >> 19;
  const float* xb = x + (size_t)bi*3*4096;
  out[idx] = b[c] + w[c*3]*xb[s] + w[c*3+1]*xb[4096+s] + w[c*3+2]*xb[8192+s];
}

// ------- sobel + concat, float4 (4 ch/thread): OUT[b][s][128] -> P[b][s][384] bf16 -------
__global__ __launch_bounds__(256) void k_sobel4(const float* __restrict__ src,
    bf16* __restrict__ p, int H, int S){
  int idx = blockIdx.x*256 + threadIdx.x;          // 16*S*32 threads
  int c4 = (idx & 31) * 4;
  int s = (idx >> 5) % S;
  int b = idx / (S*32);
  int y = s / H, x = s - y*H;
  const float* sb = src + (size_t)b*S*128 + c4;
  float4 n[3][3];
  #pragma unroll
  for (int dy=0; dy<3; dy++)
    #pragma unroll
    for (int dx=0; dx<3; dx++){
      int yy = y + dy - 1, xx = x + dx - 1;
      if (yy>=0 && yy<H && xx>=0 && xx<H)
        n[dy][dx] = *reinterpret_cast<const float4*>(sb + (size_t)(yy*H+xx)*128);
      else
        n[dy][dx] = (float4){0.f,0.f,0.f,0.f};
    }
  float v0[4], sx[4], sy[4];
  #pragma unroll
  for (int q = 0; q < 4; q++){
    float e00=((const float*)&n[0][0])[q], e01=((const float*)&n[0][1])[q], e02=((const float*)&n[0][2])[q];
    float e10=((const float*)&n[1][0])[q], e11=((const float*)&n[1][1])[q], e12=((const float*)&n[1][2])[q];
    float e20=((const float*)&n[2][0])[q], e21=((const float*)&n[2][1])[q], e22=((const float*)&n[2][2])[q];
    v0[q] = e11;
    sx[q] = (-e00 + e02 - 2.f*e10 + 2.f*e12 - e20 + e22) * 0.125f;
    sy[q] = (-e00 - 2.f*e01 - e02 + e20 + 2.f*e21 + e22) * 0.125f;
  }
  bf16* pb = p + ((size_t)b*S + s)*384;
  union { unsigned long long u; bf16 e[4]; } o0, o1, o2;
  #pragma unroll
  for (int q = 0; q < 4; q++){
    o0.e[q] = __float2bfloat16(v0[q]);
    o1.e[q] = __float2bfloat16(sx[q]);
    o2.e[q] = __float2bfloat16(sy[q]);
  }
  *reinterpret_cast<unsigned long long*>(pb + c4)       = o0.u;
  *reinterpret_cast<unsigned long long*>(pb + 128 + c4) = o1.u;
  *reinterpret_cast<unsigned long long*>(pb + 256 + c4) = o2.u;
}

// ---------------- per-(b,c) sums over s of P: SUMS[b][384][2] (pre-zeroed) ----------------
__global__ __launch_bounds__(256) void k_stats(const bf16* __restrict__ P_,
    float* __restrict__ SUMS, int S){
  __shared__ float sS[384], sQ[384];
  int b = blockIdx.y;
  int chunk = S >> 4;
  int s0 = blockIdx.x * chunk;
  int t = threadIdx.x;
  for (int i = t; i < 384; i += 256){ sS[i] = 0.f; sQ[i] = 0.f; }
  __syncthreads();
  if (t < 240){
    int oct = t % 48, ls = t / 48;
    int c8 = oct*8;
    float as[8] = {}, qs[8] = {};
    for (int s = s0 + ls; s < s0 + chunk; s += 5){
      bf8_t v = *reinterpret_cast<const bf8_t*>(P_ + ((size_t)b*S + s)*384 + c8);
      #pragma unroll
      for (int i=0;i<8;i++){ float f = b2f(v[i]); as[i]+=f; qs[i]+=f*f; }
    }
    #pragma unroll
    for (int i=0;i<8;i++){ atomicAdd(&sS[c8+i], as[i]); atomicAdd(&sQ[c8+i], qs[i]); }
  }
  __syncthreads();
  for (int i = t; i < 384; i += 256){
    atomicAdd(&SUMS[((size_t)b*384+i)*2],   sS[i]);
    atomicAdd(&SUMS[((size_t)b*384+i)*2+1], sQ[i]);
  }
}

// ------- batched hypernet v5: exact r6-v1 loop (96 VGPR, no unroll), bf16 output -------
__global__ __launch_bounds__(256) void k_hyper_all(const float* __restrict__ hw,
    const float* __restrict__ hb, const bf16* __restrict__ latb,   // [12*16][512]
    bf16* __restrict__ hk_all){                                    // [12][16][KHK] bf16
  __shared__ float Sw[128][17];
  int h0 = blockIdx.x * 128;
  int tid = threadIdx.x, wid = tid >> 6, lane = tid & 63;
  int lr = lane & 15, lg = lane >> 4;
  f4_t acc[2][12];
  #pragma unroll
  for (int f=0; f<2; f++)
    #pragma unroll
    for (int j=0; j<12; j++) acc[f][j] = (f4_t){0.f,0.f,0.f,0.f};
  for (int k0 = 0; k0 < 512; k0 += 32){
    bf8_t af[2];
    #pragma unroll
    for (int f = 0; f < 2; f++){
      int h = h0 + wid*32 + f*16 + lr;
      const float* src = hw + (size_t)h*512 + k0 + lg*8;
      float4 x0 = *reinterpret_cast<const float4*>(src);
      float4 x1 = *reinterpret_cast<const float4*>(src + 4);
      union { bf8_t v; bf16 e[8]; } o;
      o.e[0]=__float2bfloat16(x0.x); o.e[1]=__float2bfloat16(x0.y);
      o.e[2]=__float2bfloat16(x0.z); o.e[3]=__float2bfloat16(x0.w);
      o.e[4]=__float2bfloat16(x1.x); o.e[5]=__float2bfloat16(x1.y);
      o.e[6]=__float2bfloat16(x1.z); o.e[7]=__float2bfloat16(x1.w);
      af[f] = o.v;
    }
    #pragma unroll
    for (int j = 0; j < 12; j++){
      bf8_t bv = *reinterpret_cast<const bf8_t*>(latb + (size_t)(j*16 + lr)*512 + k0 + lg*8);
      acc[0][j] = __builtin_amdgcn_mfma_f32_16x16x32_bf16(af[0], bv, acc[0][j], 0, 0, 0);
      acc[1][j] = __builtin_amdgcn_mfma_f32_16x16x32_bf16(af[1], bv, acc[1][j], 0, 0, 0);
    }
  }
  for (int j = 0; j < 12; j++){
    __syncthreads();
    #pragma unroll
    for (int f = 0; f < 2; f++)
      #pragma unroll
      for (int r = 0; r < 4; r++)
        Sw[wid*32 + f*16 + lg*4 + r][lr] = acc[f][j][r];
    __syncthreads();
    int bb = tid >> 4, h8 = (tid & 15) * 8;
    union { bf8_t v; bf16 e[8]; } o;
    #pragma unroll
    for (int i = 0; i < 8; i++)
      o.e[i] = __float2bfloat16(hb[h0 + h8 + i] + Sw[h8 + i][bb]);
    *reinterpret_cast<bf8_t*>(hk_all + ((size_t)j*16 + bb)*KHK + h0 + h8) = o.v;
  }
}

// ---------------- all 12 latc GEMMs in one launch: LATB[c][b][512] bf16 ----------------
__global__ __launch_bounds__(256) void k_latall(const float* __restrict__ inj,
    const float* __restrict__ lat_w, const float* __restrict__ lat_b,
    bf16* __restrict__ LATB){
  int gwave = (int)((blockIdx.x*256 + threadIdx.x) >> 6);   // 0..6143
  int lane = threadIdx.x & 63;
  int c = gwave >> 9, o = gwave & 511;
  const float* wr = lat_w + (size_t)c*262144 + (size_t)o*512;
  float acc[16] = {};
  for (int k = lane; k < 512; k += 64){
    float wv = wr[k];
    #pragma unroll
    for (int b = 0; b < 16; b++) acc[b] += wv * inj[b*512 + k];
  }
  #pragma unroll
  for (int b = 0; b < 16; b++)
    for (int off = 32; off > 0; off >>= 1) acc[b] += __shfl_down(acc[b], off);
  if (lane == 0){
    float bv = lat_b[c*512 + o];
    #pragma unroll
    for (int b = 0; b < 16; b++)
      LATB[(size_t)c*8192 + b*512 + o] = __float2bfloat16(acc[b] + bv);
  }
}

// ------ weight transform (HK bf16): fold instnorm, stacked mats, a/g interleave ----
__global__ __launch_bounds__(256) void k_xform(
    const float* __restrict__ fc_w1, const float* __restrict__ fc_b1,
    const float* __restrict__ fc_w2, const float* __restrict__ fc_b2,
    const float* __restrict__ fc_wsc, const float* __restrict__ fc_bsc,
    const bf16* __restrict__ HK_, const float* __restrict__ SUMS, float Sf,
    bf16* __restrict__ Wstack, float* __restrict__ bstack,
    bf16* __restrict__ Wbig, float* __restrict__ bbig,
    bf16* __restrict__ Wmd, float* __restrict__ bmd){
  int gw = (blockIdx.x*256 + threadIdx.x) >> 6;
  int lane = threadIdx.x & 63;
  float invSf = 1.f / Sf;
  if (gw < 4096){                     // Wstack rows: [fc_w1 ; w_in] per batch
    int b = gw >> 8, o = gw & 255;
    const float* su = SUMS + (size_t)b*768;
    const bf16* hkb = HK_ + (size_t)b*KHK;
    float b0 = (o < 128) ? fc_b1[o] : ldf(hkb, OFF_BIN + (o-128));
    float accv = 0.f;
    bf16* dst = Wstack + ((size_t)b*256 + o)*384;
    for (int k = lane; k < 384; k += 64){
      float m = su[k*2] * invSf;
      float iv = rsqrtf(fmaxf(su[k*2+1]*invSf - m*m, 0.f) + 1e-5f);
      float wv = (o < 128) ? fc_w1[(size_t)o*384 + k]
                           : ldf(hkb, OFF_WIN + (size_t)(o-128)*384 + k);
      float w = wv * iv;
      accv += w * m;
      dst[k] = __float2bfloat16(w);
    }
    for (int off=32; off>0; off>>=1) accv += __shfl_down(accv, off);
    if (lane==0) bstack[b*256+o] = b0 - accv;
  } else if (gw < 8192){              // Wbig rows: [fc_wsc+w_sc | fc_w2 | w_ot], a/g interleave
    int r = gw - 4096; int b = r >> 8, o = r & 255;
    const float* su = SUMS + (size_t)b*768;
    const bf16* hkb = HK_ + (size_t)b*KHK;
    int cc = o & 127;
    int nr = ((cc >> 4) << 5) + ((o >> 7) << 4) + (cc & 15);   // 16-row a/g interleave
    bf16* dst = Wbig + ((size_t)b*256 + nr)*640;
    float accv = 0.f;
    for (int k = lane; k < 384; k += 64){
      float m = su[k*2] * invSf;
      float iv = rsqrtf(fmaxf(su[k*2+1]*invSf - m*m, 0.f) + 1e-5f);
      float w = (fc_wsc[(size_t)o*384 + k] + ldf(hkb, OFF_WSC + (size_t)o*384 + k)) * iv;
      accv += w * m;
      dst[k] = __float2bfloat16(w);
    }
    for (int k = lane; k < 128; k += 64){
      dst[384+k] = __float2bfloat16(fc_w2[(size_t)o*128 + k]);
      dst[512+k] = hkb[OFF_WOT + (size_t)o*128 + k];
    }
    for (int off=32; off>0; off>>=1) accv += __shfl_down(accv, off);
    if (lane==0) bbig[b*256+nr] = fc_bsc[o] + ldf(hkb, OFF_BSC+o) + fc_b2[o]
                                  + ldf(hkb, OFF_BOT+o) - accv;
  } else {                            // Wmd rows
    int r = gw - 8192; int b = r >> 7, o = r & 127;
    const bf16* hkb = HK_ + (size_t)b*KHK;
    bf16* dst = Wmd + ((size_t)b*128 + o)*128;
    for (int k = lane; k < 128; k += 64)
      dst[k] = hkb[OFF_WMD + (size_t)o*128 + k];
    if (lane==0) bmd[b*128+o] = ldf(hkb, OFF_BMD + o);
  }
}

// ====== fully fused per-cell GEMM chain (512 threads, HG never leaves LDS) ======
// gemm1: H1/Hm = relu(bstk + P*Wstk)  -> LDS tiles
// phase A: G2 = relu(bmd + Hm*Wmd)    -> overwrites Hm tile
// phase B: gated 3-seg {P, H1(LDS), G2(LDS)} * Wbig -> OUT += leak*a*sigmoid(g)
__global__ __launch_bounds__(512) void k_cellgemm(
    const bf16* __restrict__ P_,
    const bf16* __restrict__ Wstk, const float* __restrict__ bstk,
    const bf16* __restrict__ Wmd, const float* __restrict__ bmd,
    const bf16* __restrict__ Wbig, const float* __restrict__ bbig,
    float* __restrict__ OUTf, int S, const float* __restrict__ leakp){
  __shared__ short As[128][32];      // 8KB  staging (A operand)
  __shared__ short Bs[256][32];      // 16KB staging (B operand)
  __shared__ short H1t[128][136];    // 34.8KB H1 tile (bf16)
  __shared__ short HmG[128][136];    // 34.8KB Hm tile, later G2 tile (bf16)
  int b = blockIdx.z, s0 = blockIdx.x * 128;
  int tid = threadIdx.x, wid = tid >> 6, lane = tid & 63;
  int lr = lane & 15, lg = lane >> 4;
  int r0 = tid >> 2, c8 = (tid & 3) * 8;
  bf16* H1b = (bf16*)&H1t[0][0];
  bf16* HmGb = (bf16*)&HmG[0][0];
  int wrow = (wid >> 2) * 64, wcol = (wid & 3) * 64;   // 2x4 wave grid (gemm1, phase B)
  f4_t acc[4][4] = {{}};
  // ---- gemm1: 128s x 256n tile of HG, K=384
  {
    const bf16* gA  = P_ + ((size_t)b*S + s0 + r0) * 384 + c8;
    const bf16* gB0 = Wstk + (size_t)b*98304 + (size_t)r0 * 384 + c8;
    const bf16* gB1 = gB0 + (size_t)128 * 384;
    for (int k0 = 0; k0 < 384; k0 += 32){
      gld_lds16(gA + k0,  &As[wid*16][0]);
      gld_lds16(gB0 + k0, &Bs[wid*16][0]);
      gld_lds16(gB1 + k0, &Bs[128 + wid*16][0]);
      __syncthreads();
      bf8_t af[4], bfv[4];
      #pragma unroll
      for (int i = 0; i < 4; i++) af[i]  = *(const bf8_t*)(&As[wrow + i*16 + lr][lg*8]);
      #pragma unroll
      for (int j = 0; j < 4; j++) bfv[j] = *(const bf8_t*)(&Bs[wcol + j*16 + lr][lg*8]);
      #pragma unroll
      for (int i = 0; i < 4; i++)
        #pragma unroll
        for (int j = 0; j < 4; j++)
          acc[i][j] = __builtin_amdgcn_mfma_f32_16x16x32_bf16(af[i], bfv[j], acc[i][j], 0, 0, 0);
      __syncthreads();
    }
    // write relu(acc+bias) into H1t (n<128) / HmG (n>=128)
    #pragma unroll
    for (int j = 0; j < 4; j++){
      int n = wcol + j*16 + lr;
      float bv = bstk[(size_t)b*256 + n];
      bf16* dst = (n < 128) ? H1b : HmGb;
      int col = n & 127;
      #pragma unroll
      for (int i = 0; i < 4; i++){
        int row = wrow + i*16 + lg*4;
        #pragma unroll
        for (int r = 0; r < 4; r++)
          stf(dst, (size_t)(row + r)*136 + col, fmaxf(acc[i][j][r] + bv, 0.f));
      }
    }
    __syncthreads();
  }
  // ---- phase A: G2 = relu(bmd + Hm*Wmd); 4x2 wave grid (32s x 64n per wave)
  {
    int wrowA = (wid >> 1) * 32, wcolA = (wid & 1) * 64;
    f4_t accA[2][4] = {{}};
    const bf16* gB = Wmd + (size_t)b*16384 + (size_t)r0 * 128 + c8;
    for (int k0 = 0; k0 < 128; k0 += 32){
      gld_lds16(gB + k0, &Bs[wid*16][0]);
      __syncthreads();
      bf8_t af[2], bfv[4];
      #pragma unroll
      for (int i = 0; i < 2; i++)
        af[i] = *(const bf8_t*)(&HmG[wrowA + i*16 + lr][k0 + lg*8]);
      #pragma unroll
      for (int j = 0; j < 4; j++) bfv[j] = *(const bf8_t*)(&Bs[wcolA + j*16 + lr][lg*8]);
      #pragma unroll
      for (int i = 0; i < 2; i++)
        #pragma unroll
        for (int j = 0; j < 4; j++)
          accA[i][j] = __builtin_amdgcn_mfma_f32_16x16x32_bf16(af[i], bfv[j], accA[i][j], 0, 0, 0);
      __syncthreads();
    }
    // all Hm reads done (barrier above) -> overwrite HmG with G2
    const float* bmdb = bmd + b*128;
    #pragma unroll
    for (int j = 0; j < 4; j++){
      int col = wcolA + j*16 + lr;
      float bv = bmdb[col];
      #pragma unroll
      for (int i = 0; i < 2; i++){
        int row = wrowA + i*16 + lg*4;
        #pragma unroll
        for (int r = 0; r < 4; r++)
          stf(HmGb, (size_t)(row + r)*136 + col, fmaxf(accA[i][j][r] + bv, 0.f));
      }
    }
    __syncthreads();
  }
  // ---- phase B: segs {P(384), H1t(128 LDS), G2=HmG(128 LDS)} x Wbig
  #pragma unroll
  for (int i = 0; i < 4; i++)
    #pragma unroll
    for (int j = 0; j < 4; j++)
      acc[i][j] = (f4_t){0.f,0.f,0.f,0.f};
  const bf16* Wb = Wbig + (size_t)b * 163840;
  {   // seg 1: P (stage A+B)
    const bf16* gA  = P_ + ((size_t)b*S + s0 + r0) * 384 + c8;
    const bf16* gB0 = Wb + (size_t)r0 * 640 + c8;
    const bf16* gB1 = Wb + (size_t)(128 + r0) * 640 + c8;
    for (int k0 = 0; k0 < 384; k0 += 32){
      gld_lds16(gA + k0,  &As[wid*16][0]);
      gld_lds16(gB0 + k0, &Bs[wid*16][0]);
      gld_lds16(gB1 + k0, &Bs[128 + wid*16][0]);
      __syncthreads();
      bf8_t af[4], bfv[4];
      #pragma unroll
      for (int i = 0; i < 4; i++) af[i]  = *(const bf8_t*)(&As[wrow + i*16 + lr][lg*8]);
      #pragma unroll
      for (int j = 0; j < 4; j++) bfv[j] = *(const bf8_t*)(&Bs[wcol + j*16 + lr][lg*8]);
      #pragma unroll
      for (int i = 0; i < 4; i++)
        #pragma unroll
        for (int j = 0; j < 4; j++)
          acc[i][j] = __builtin_amdgcn_mfma_f32_16x16x32_bf16(af[i], bfv[j], acc[i][j], 0, 0, 0);
      __syncthreads();
    }
  }
  {   // seg 2: H1 from LDS (A), Wbig cols 384..512 (B staged)
    const bf16* gB0 = Wb + (size_t)r0 * 640 + 384 + c8;
    const bf16* gB1 = Wb + (size_t)(128 + r0) * 640 + 384 + c8;
    for (int k0 = 0; k0 < 128; k0 += 32){
      gld_lds16(gB0 + k0, &Bs[wid*16][0]);
      gld_lds16(gB1 + k0, &Bs[128 + wid*16][0]);
      __syncthreads();
      bf8_t af[4], bfv[4];
      #pragma unroll
      for (int i = 0; i < 4; i++) af[i]  = *(const bf8_t*)(&H1t[wrow + i*16 + lr][k0 + lg*8]);
      #pragma unroll
      for (int j = 0; j < 4; j++) bfv[j] = *(const bf8_t*)(&Bs[wcol + j*16 + lr][lg*8]);
      #pragma unroll
      for (int i = 0; i < 4; i++)
        #pragma unroll
        for (int j = 0; j < 4; j++)
          acc[i][j] = __builtin_amdgcn_mfma_f32_16x16x32_bf16(af[i], bfv[j], acc[i][j], 0, 0, 0);
      __syncthreads();
    }
  }
  {   // seg 3: G2 from LDS (A), Wbig cols 512..640 (B staged)
    const bf16* gB0 = Wb + (size_t)r0 * 640 + 512 + c8;
    const bf16* gB1 = Wb + (size_t)(128 + r0) * 640 + 512 + c8;
    for (int k0 = 0; k0 < 128; k0 += 32){
      gld_lds16(gB0 + k0, &Bs[wid*16][0]);
      gld_lds16(gB1 + k0, &Bs[128 + wid*16][0]);
      __syncthreads();
      bf8_t af[4], bfv[4];
      #pragma unroll
      for (int i = 0; i < 4; i++) af[i]  = *(const bf8_t*)(&HmG[wrow + i*16 + lr][k0 + lg*8]);
      #pragma unroll
      for (int j = 0; j < 4; j++) bfv[j] = *(const bf8_t*)(&Bs[wcol + j*16 + lr][lg*8]);
      #pragma unroll
      for (int i = 0; i < 4; i++)
        #pragma unroll
        for (int j = 0; j < 4; j++)
          acc[i][j] = __builtin_amdgcn_mfma_f32_16x16x32_bf16(af[i], bfv[j], acc[i][j], 0, 0, 0);
      __syncthreads();
    }
  }
  // gated epilogue: interleaved a/g cols -> OUT += leak*a*sigmoid(g)
  float leak = fminf(fmaxf(leakp[0], 0.001f), 1000.f);
  #pragma unroll
  for (int jp = 0; jp < 2; jp++){
    int na = wcol + jp*32 + lr;
    float bva = bbig[(size_t)b * 256 + na];
    float bvg = bbig[(size_t)b * 256 + na + 16];
    int chan = (wcol >> 1) + jp*16 + lr;
    #pragma unroll
    for (int i = 0; i < 4; i++){
      int sr = s0 + wrow + i*16 + lg*4;
      #pragma unroll
      for (int r = 0; r < 4; r++){
        float av = acc[i][jp*2][r]   + bva;
        float gv = acc[i][jp*2+1][r] + bvg;
        size_t oidx = ((size_t)b * S + sr + r) * 128 + chan;
        OUTf[oidx] += leak * av * (1.f / (1.f + expf(-gv)));
      }
    }
  }
}

// ------ head MFMA GEMM (256-thread, m97 staging) ------
template<int RELU, class TOUT>
__global__ __launch_bounds__(256) void k_mfgemm(
    Seg s1, const bf16* __restrict__ W, long long wbstride, int Ktot,
    const float* __restrict__ bias, int bbstride,
    TOUT* __restrict__ OUTp, int ldc, int Mout, int S){
  __shared__ short As[128][32];
  __shared__ short Bs[128][32];
  int b  = blockIdx.z;
  int s0 = blockIdx.x * 128;
  int n0 = blockIdx.y * 128;
  int tid = threadIdx.x;
  int wid = tid >> 6, lane = tid & 63;
  int wrow = (wid >> 1) * 64;
  int wcol = (wid & 1) * 64;
  int lr = lane & 15, lg = lane >> 4;
  int r0 = wid*32 + (lane >> 2);
  int c8 = (lane & 3) * 8;
  const bf16* Wb = W + (size_t)b * wbstride;
  f4_t acc[4][4] = {{}};
  const bf16* INb = s1.p + (size_t)b * S * s1.ld;
  const bf16* gA0 = INb + (size_t)(s0 + r0) * s1.ld + c8;
  const bf16* gA1 = INb + (size_t)(s0 + r0 + 16) * s1.ld + c8;
  const bf16* gB0 = Wb + (size_t)(n0 + r0) * Ktot + c8;
  const bf16* gB1 = Wb + (size_t)(n0 + r0 + 16) * Ktot + c8;
  for (int k0 = 0; k0 < s1.klen; k0 += 32){
    gld_lds16(gA0 + k0, &As[wid*32][0]);
    gld_lds16(gA1 + k0, &As[wid*32 + 16][0]);
    gld_lds16(gB0 + k0, &Bs[wid*32][0]);
    gld_lds16(gB1 + k0, &Bs[wid*32 + 16][0]);
    __syncthreads();
    bf8_t af[4], bfv[4];
    #pragma unroll
    for (int i = 0; i < 4; i++) af[i]  = *(const bf8_t*)(&As[wrow + i*16 + lr][lg*8]);
    #pragma unroll
    for (int j = 0; j < 4; j++) bfv[j] = *(const bf8_t*)(&Bs[wcol + j*16 + lr][lg*8]);
    #pragma unroll
    for (int i = 0; i < 4; i++)
      #pragma unroll
      for (int j = 0; j < 4; j++)
        acc[i][j] = __builtin_amdgcn_mfma_f32_16x16x32_bf16(af[i], bfv[j], acc[i][j], 0, 0, 0);
    __syncthreads();
  }
  #pragma unroll
  for (int j = 0; j < 4; j++){
    int n = n0 + wcol + j*16 + lr;
    if (n >= Mout) continue;
    float bv = bias[(size_t)b * bbstride + n];
    #pragma unroll
    for (int i = 0; i < 4; i++){
      int sr = s0 + wrow + i*16 + lg*4;
      size_t base = ((size_t)b * S + sr) * ldc + n;
      #pragma unroll
      for (int r = 0; r < 4; r++){
        float v = acc[i][j][r] + bv;
        if (RELU) v = fmaxf(v, 0.f);
        stf(OUTp, base + (size_t)r * ldc, v);
      }
    }
  }
}

// ---------------- fused gaussian blur + 2x2 mean pool, channel-last ----------------
__global__ __launch_bounds__(256) void k_blurpool(const float* __restrict__ src,
    float* __restrict__ dst, int H2, int S2){
  const float g[3] = {0.27406862f, 0.45186276f, 0.27406862f};
  int idx = blockIdx.x*256 + threadIdx.x;   // 16*S2*128
  int c = idx & 127;
  int s2 = (idx >> 7) % S2;
  int b = idx / (S2*128);
  int y2 = s2 / H2, x2 = s2 - y2*H2;
  int H = H2*2;
  const float* sb = src + (size_t)b*(H*H)*128 + c;
  float acc = 0.f;
  #pragma unroll
  for (int dy2 = 0; dy2 < 2; dy2++)
    #pragma unroll
    for (int dx2 = 0; dx2 < 2; dx2++){
      int y = 2*y2 + dy2, x = 2*x2 + dx2;
      float bl = 0.f;
      #pragma unroll
      for (int i = 0; i < 3; i++)
        #pragma unroll
        for (int j = 0; j < 3; j++){
          int yy = y + i - 1, xx = x + j - 1;
          float v = (yy>=0 && yy<H && xx>=0 && xx<H) ? sb[(size_t)(yy*H+xx)*128] : 0.f;
          bl += v * g[i] * g[j];
        }
      acc += bl;
    }
  dst[idx] = acc * 0.25f;
}

// ---------------- add seed + fp32->bf16 in one pass ----------------
__global__ __launch_bounds__(256) void k_seedcvt(const float* __restrict__ in,
    const float* __restrict__ seed, bf16* __restrict__ out){
  int idx = blockIdx.x*256 + threadIdx.x;   // 16*256*128
  int c = idx & 127;
  int s = (idx >> 7) & 255;
  out[idx] = __float2bfloat16(in[idx] + seed[c*256 + s]);
}

// ---------------- build cs (16,4480) from Ohead [16][256][385] ----------------
__global__ __launch_bounds__(256) void k_build_cs(const float* __restrict__ O,
    float* __restrict__ cs){
  int b = blockIdx.x;
  const float* Ob = O + (size_t)b*256*385;
  for (int id = threadIdx.x; id < 4480; id += 256){
    float v;
    if (id < 128){
      float s = 0; for (int t = 0; t < 256; t++) s += Ob[(size_t)t*385 + id];
      v = s * (1.f/256.f);
    } else if (id < 2176){
      int r = id - 128; int c = r >> 4, h = r & 15;
      float s = 0; for (int w = 0; w < 16; w++) s += Ob[(size_t)(h*16+w)*385 + 128 + c];
      v = s * (1.f/16.f);
    } else if (id < 4224){
      int r = id - 2176; int c = r >> 4, w = r & 15;
      float s = 0; for (int h = 0; h < 16; h++) s += Ob[(size_t)(h*16+w)*385 + 256 + c];
      v = s * (1.f/16.f);
    } else {
      v = Ob[(size_t)(id - 4224)*385 + 384];
    }
    cs[b*4480 + id] = v;
  }
}

// ---------------- small 16-row GEMM: one wave per output row of W ----------------
template<int RELU, int ACCUM, class TOUT>
__global__ __launch_bounds__(256) void k_rowgemm(const float* __restrict__ IN, // [16][K]
    const float* __restrict__ W,    // [M][K]
    const float* __restrict__ bias, // [M]
    TOUT* __restrict__ OUT, int M, int K){
  int wave = (int)((blockIdx.x*256 + threadIdx.x) >> 6);
  int lane = threadIdx.x & 63;
  if (wave >= M) return;
  const float* wr = W + (size_t)wave*K;
  float acc[16] = {};
  for (int k = lane; k < K; k += 64){
    float wv = wr[k];
    #pragma unroll
    for (int b = 0; b < 16; b++) acc[b] += wv * IN[b*K + k];
  }
  #pragma unroll
  for (int b = 0; b < 16; b++)
    for (int off = 32; off > 0; off >>= 1) acc[b] += __shfl_down(acc[b], off);
  if (lane == 0){
    float bv = bias[wave];
    #pragma unroll
    for (int b = 0; b < 16; b++){
      float v = acc[b] + bv;
      if (RELU) v = fmaxf(v, 0.f);
      size_t oi = (size_t)b*M + wave;
      if (ACCUM) v += ldf(OUT, oi);
      stf(OUT, oi, v);
    }
  }
}

// ------- dual 16-row GEMM: waves [0,M1) -> set1 (RELU1), waves [M1,M1+M2) -> set2 -------
template<int RELU1>
__global__ __launch_bounds__(256) void k_rowgemm2(const float* __restrict__ IN,
    const float* __restrict__ W1, const float* __restrict__ b1, float* __restrict__ O1, int M1,
    const float* __restrict__ W2, const float* __restrict__ b2, float* __restrict__ O2, int M2,
    int K){
  int wave = (int)((blockIdx.x*256 + threadIdx.x) >> 6);
  int lane = threadIdx.x & 63;
  if (wave >= M1 + M2) return;
  int second = (wave >= M1);
  int o = second ? (wave - M1) : wave;
  const float* wr = (second ? W2 : W1) + (size_t)o*K;
  float acc[16] = {};
  for (int k = lane; k < K; k += 64){
    float wv = wr[k];
    #pragma unroll
    for (int b = 0; b < 16; b++) acc[b] += wv * IN[b*K + k];
  }
  #pragma unroll
  for (int b = 0; b < 16; b++)
    for (int off = 32; off > 0; off >>= 1) acc[b] += __shfl_down(acc[b], off);
  if (lane == 0){
    float bv = second ? b2[o] : b1[o];
    float* OUT = second ? O2 : O1;
    int M = second ? M2 : M1;
    #pragma unroll
    for (int b = 0; b < 16; b++){
      float v = acc[b] + bv;
      if (RELU1 && !second) v = fmaxf(v, 0.f);
      OUT[(size_t)b*M + o] = v;
    }
  }
}

extern "C" void kernel_launch(void* const* d_in, const int* in_sizes, int n_in,
                              void* d_out, int out_size, void* d_ws, size_t ws_size,
                              hipStream_t stream){
  (void)in_sizes; (void)n_in; (void)out_size; (void)ws_size;
  const float* x      = (const float*)d_in[0];
  const float* inj    = (const float*)d_in[1];
  const float* leakp  = (const float*)d_in[2];
  const float* in_w   = (const float*)d_in[3];
  const float* in_b   = (const float*)d_in[4];
  const float* fc_w1  = (const float*)d_in[5];
  const float* fc_b1  = (const float*)d_in[6];
  const float* fc_w2  = (const float*)d_in[7];
  const float* fc_b2  = (const float*)d_in[8];
  const float* fc_wsc = (const float*)d_in[9];
  const float* fc_bsc = (const float*)d_in[10];
  const float* hyp_w  = (const float*)d_in[11];
  const float* hyp_b  = (const float*)d_in[12];
  const float* lat_w  = (const float*)d_in[13];
  const float* lat_b  = (const float*)d_in[14];
  const float* seed   = (const float*)d_in[15];
  const float* out_w  = (const float*)d_in[16];
  const float* out_b  = (const float*)d_in[17];
  const float* l1_w1  = (const float*)d_in[18];
  const float* l1_b1  = (const float*)d_in[19];
  const float* l1_w2  = (const float*)d_in[20];
  const float* l1_b2  = (const float*)d_in[21];
  const float* l1_wsc = (const float*)d_in[22];
  const float* l1_bsc = (const float*)d_in[23];
  const float* l2_w1  = (const float*)d_in[24];
  const float* l2_b1  = (const float*)d_in[25];
  const float* l2_w2  = (const float*)d_in[26];
  const float* l2_b2  = (const float*)d_in[27];
  const float* l2_wsc = (const float*)d_in[28];
  const float* l2_bsc = (const float*)d_in[29];
  const float* fin_w  = (const float*)d_in[30];
  const float* fin_b  = (const float*)d_in[31];

  char* ws = (char*)d_ws;
  float* OUT    = (float*)(ws);                      // 32MB  [16][4096][128] fp32
  bf16*  P      = (bf16*)(ws + 33554432UL);          // 48MB  [16][4096][384]
  bf16*  HKALL  = (bf16*)(ws + 134217728UL);         // 75.8MB [12][16][197376] bf16
  bf16*  WSTK   = (bf16*)(ws + 285802496UL);         // 3.1MB [16][256][384]
  bf16*  WBIG   = (bf16*)(ws + 288948224UL);         // 5.2MB [16][256][640]
  bf16*  WMD    = (bf16*)(ws + 294191104UL);         // 512KB [16][128][128]
  float* BSTK   = (float*)(ws + 294715392UL);        // [16][256]
  float* BBIG   = (float*)(ws + 294731776UL);        // [16][256]
  float* BMD    = (float*)(ws + 294748160UL);        // [16][128]
  bf16*  LATB   = (bf16*)(ws + 294805504UL);         // [12][16][512]
  bf16*  OUTB   = (bf16*)(ws + 295002112UL);         // [16][256][128]
  float* OHEAD  = (float*)(ws + 296050688UL);        // [16][256][385]
  bf16*  OWB    = (bf16*)(ws + 302358528UL);         // [385][128]
  float* CS     = (float*)(ws + 302457088UL);        // [16][4480]
  float* T1     = (float*)(ws + 302743808UL);        // [16][1024]
  float* HCS    = (float*)(ws + 302809344UL);        // [16][512]
  float* HCS2   = (float*)(ws + 302842112UL);        // [16][512]
  float* SUMS12 = (float*)(ws + 302874880UL);        // 576KB [12][16][384][2]
  float* OUT2   = (float*)(ws + 310378496UL);        // 32MB alt state buffer

  k_cvt_bf16<<<32, 256, 0, stream>>>(out_w, OWB, 49280ULL);
  k_in_conv<<<32768, 256, 0, stream>>>(x, in_w, in_b, OUT);

  k_latall<<<1536, 256, 0, stream>>>(inj, lat_w, lat_b, LATB);
  k_hyper_all<<<1542, 256, 0, stream>>>(hyp_w, hyp_b, LATB, HKALL);
  (void)hipMemsetAsync(SUMS12, 0, 12*16*384*2*sizeof(float), stream);   // all cells, once

  float* cur = OUT;
  float* alt = OUT2;
  int H = 64;
  for (int c = 0; c < 12; c++){
    int S = H*H;
    float* SUMS = SUMS12 + (size_t)c*16*768;
    k_sobel4<<<(16*S*32)/256, 256, 0, stream>>>(cur, P, H, S);
    k_stats<<<dim3(16,16), 256, 0, stream>>>(P, SUMS, S);
    k_xform<<<2560, 256, 0, stream>>>(fc_w1, fc_b1, fc_w2, fc_b2, fc_wsc, fc_bsc,
                                      HKALL + (size_t)c*16*KHK, SUMS, (float)S,
                                      WSTK, BSTK, WBIG, BBIG, WMD, BMD);
    k_cellgemm<<<dim3(S/128, 1, 16), 512, 0, stream>>>(
        P, WSTK, BSTK, WMD, BMD, WBIG, BBIG, cur, S, leakp);
    if (c == 3 || c == 7){
      int H2 = H/2, S2 = S/4;
      k_blurpool<<<(16*S2*128)/256, 256, 0, stream>>>(cur, alt, H2, S2);
      float* t = cur; cur = alt; alt = t;
      H = H2;
    }
  }

  k_seedcvt<<<2048, 256, 0, stream>>>(cur, seed, OUTB);
  Seg segO = {OUTB, 128, 128};
  k_mfgemm<0,float><<<dim3(2, 4, 16), 256, 0, stream>>>(
      segO, OWB, 0LL, 128, out_b, 0, OHEAD, 385, 385, 256);
  k_build_cs<<<16, 256, 0, stream>>>(OHEAD, CS);

  // head MLP: 5 launches (dual-matrix fusion where inputs match)
  k_rowgemm2<1><<<384, 256, 0, stream>>>(CS, l1_w1, l1_b1, T1, 1024,
                                         l1_wsc, l1_bsc, HCS, 512, 4480);
  k_rowgemm<0,1,float><<<128, 256, 0, stream>>>(T1, l1_w2, l1_b2, HCS, 512, 1024);
  k_rowgemm2<1><<<256, 256, 0, stream>>>(HCS, l2_w1, l2_b1, T1, 512,
                                         l2_wsc, l2_bsc, HCS2, 512, 512);
  k_rowgemm<0,1,float><<<128, 256, 0, stream>>>(T1, l2_w2, l2_b2, HCS2, 512, 512);
  k_rowgemm<0,0,float><<<128, 256, 0, stream>>>(HCS2, fin_w, fin_b, (float*)d_out, 512, 512);
}